// Round 2
// baseline (412.557 us; speedup 1.0000x reference)
//
#include <hip/hip_runtime.h>
#include <hip/hip_bf16.h>

// Problem constants (from reference setup_inputs)
#define BB 4
#define CIN 64
#define HH 160
#define WW 160
#define COUT 64
#define K2 9
#define HWD (HH * WW)                   // 25600
#define OUT_ELEMS (BB * COUT * HWD)     // 6,553,600
#define OFF_ELEMS (BB * 18 * HWD)       // 1,843,200
#define EPSBN 1e-5f

// ---------------------------------------------------------------------------
// prep: transpose weights to [c][k][o] (o contiguous -> wave-uniform scalar
// loads in the hot loops), and zero the BN double accumulators.
// ws layout (floats): wct[64*9*64]=36864 | wot[64*9*18]=10368 | 128 doubles
// ---------------------------------------------------------------------------
__global__ void prep_kernel(const float* __restrict__ cw,
                            const float* __restrict__ ow,
                            float* __restrict__ wct,
                            float* __restrict__ wot,
                            double* __restrict__ sums) {
  int i = blockIdx.x * 256 + threadIdx.x;
  if (i < 36864) {                       // conv_w [o][c][k] -> wct[(c*9+k)*64+o]
    int o = i / 576, r = i % 576, c = r / 9, k = r % 9;
    wct[(c * 9 + k) * 64 + o] = cw[i];
  }
  if (i < 10368) {                       // offset_w [o][c][k] -> wot[(c*9+k)*18+o]
    int o = i / 576, r = i % 576, c = r / 9, k = r % 9;
    wot[(c * 9 + k) * 18 + o] = ow[i];
  }
  if (i < 128) sums[i] = 0.0;
}

// ---------------------------------------------------------------------------
// offset conv, channel-split x4: block z = b*4 + cbi, each block reduces 16
// input channels of a 16x16 tile and atomicAdds partial sums into the
// (zero-inited) offset region of d_out. Clamp happens in clamp_kernel.
// grid: 10 x 10 x 16 = 1600 blocks.
// ---------------------------------------------------------------------------
__global__ __launch_bounds__(256) void offconv_kernel(
    const float* __restrict__ d, const float* __restrict__ wot,
    float* __restrict__ off_accum) {
  const int bz = blockIdx.z;
  const int b = bz >> 2, cb = (bz & 3) * 16;
  const int tx0 = blockIdx.x * 16, ty0 = blockIdx.y * 16;
  const int tx = threadIdx.x & 15, ty = threadIdx.x >> 4;

  __shared__ float patch[16 * 324];      // 16 ch x 18x18 = 20.7 KB

  float acc[18];
#pragma unroll
  for (int o = 0; o < 18; ++o) acc[o] = 0.f;

  for (int l = threadIdx.x; l < 16 * 324; l += 256) {
    int c = l / 324, rc = l % 324, r = rc / 18, col = rc % 18;
    int gy = ty0 - 1 + r, gx = tx0 - 1 + col;
    float v = 0.f;
    if (gy >= 0 && gy < HH && gx >= 0 && gx < WW)
      v = d[((b * 64 + cb + c) * HH + gy) * WW + gx];
    patch[l] = v;
  }
  __syncthreads();

  for (int c = 0; c < 16; ++c) {
#pragma unroll
    for (int k = 0; k < 9; ++k) {
      const int kh = k / 3, kw = k % 3;
      float v = patch[c * 324 + (ty + kh) * 18 + tx + kw];
      const float* wp = wot + ((cb + c) * 9 + k) * 18;  // wave-uniform
#pragma unroll
      for (int o = 0; o < 18; ++o) acc[o] = fmaf(v, wp[o], acc[o]);
    }
  }
  const int h = ty0 + ty, w = tx0 + tx;
#pragma unroll
  for (int o = 0; o < 18; ++o)
    atomicAdd(&off_accum[((b * 18 + o) * HH + h) * WW + w], acc[o]);
}

// clamp offsets in place to [-1,1] (after atomic accumulation completes)
__global__ __launch_bounds__(256) void clamp_kernel(float* __restrict__ off) {
  int i = blockIdx.x * 256 + threadIdx.x;   // over OFF_ELEMS/4
  if (i >= OFF_ELEMS / 4) return;
  float4 v = ((float4*)off)[i];
  v.x = fminf(1.f, fmaxf(-1.f, v.x));
  v.y = fminf(1.f, fmaxf(-1.f, v.y));
  v.z = fminf(1.f, fmaxf(-1.f, v.z));
  v.w = fminf(1.f, fmaxf(-1.f, v.w));
  ((float4*)off)[i] = v;
}

// ---------------------------------------------------------------------------
// deformable conv, channel-split x4: block z = b*4 + cbi; each block reduces
// 16 input channels (two 8-channel LDS chunks, 14.1 KB -> 11 blocks/CU cap)
// of a 16x16 tile, atomicAdds into zero-inited out. Offsets clamped to
// [-1,1] guarantee all bilinear corners live in a 21x21 patch (zero-padded
// => reference's zero-pad gather semantics, no bounds checks in hot loop).
// grid: 10 x 10 x 16 = 1600 blocks.
// ---------------------------------------------------------------------------
__global__ __launch_bounds__(256) void dconv_kernel(
    const float* __restrict__ x, const float* __restrict__ offs,
    const float* __restrict__ wct, float* __restrict__ out) {
  const int bz = blockIdx.z;
  const int b = bz >> 2, cb0 = (bz & 3) * 16;
  const int tx0 = blockIdx.x * 16, ty0 = blockIdx.y * 16;
  const int tx = threadIdx.x & 15, ty = threadIdx.x >> 4;
  const int h = ty0 + ty, w = tx0 + tx;

  // Per-tap: patch-relative corner base + 4 bilinear weights.
  int bse[9];
  float w00[9], w01[9], w10[9], w11[9];
#pragma unroll
  for (int k = 0; k < 9; ++k) {
    const int kh = k / 3, kw = k % 3;
    float dy = offs[((b * 18 + 2 * k) * HH + h) * WW + w];
    float dx = offs[((b * 18 + 2 * k + 1) * HH + h) * WW + w];
    float py = (float)(h - 1 + kh) + dy;
    float px = (float)(w - 1 + kw) + dx;
    float y0f = floorf(py), x0f = floorf(px);
    float wy = py - y0f, wx = px - x0f;
    int ry = (int)y0f - (ty0 - 2);   // in [0,19] by clamp guarantee
    int rx = (int)x0f - (tx0 - 2);
    bse[k] = ry * 21 + rx;
    w00[k] = (1.f - wy) * (1.f - wx);
    w01[k] = (1.f - wy) * wx;
    w10[k] = wy * (1.f - wx);
    w11[k] = wy * wx;
  }

  __shared__ float patch[8 * 441];   // 8 ch x 21x21 = 14.1 KB

  float acc[64];
#pragma unroll
  for (int o = 0; o < 64; ++o) acc[o] = 0.f;

  for (int cc = 0; cc < 2; ++cc) {
    const int cbase = cb0 + cc * 8;
    __syncthreads();
    for (int l = threadIdx.x; l < 8 * 441; l += 256) {
      int c = l / 441, rc = l % 441, r = rc / 21, col = rc % 21;
      int gy = ty0 - 2 + r, gx = tx0 - 2 + col;
      float v = 0.f;
      if (gy >= 0 && gy < HH && gx >= 0 && gx < WW)
        v = x[((b * 64 + cbase + c) * HH + gy) * WW + gx];
      patch[l] = v;
    }
    __syncthreads();
    for (int c = 0; c < 8; ++c) {
      const float* pc = patch + c * 441;
#pragma unroll
      for (int k = 0; k < 9; ++k) {
        const int bs = bse[k];
        float v00 = pc[bs], v01 = pc[bs + 1];
        float v10 = pc[bs + 21], v11 = pc[bs + 22];
        float val = w00[k] * v00 + w01[k] * v01 + w10[k] * v10 + w11[k] * v11;
        const float* wp = wct + ((cbase + c) * 9 + k) * 64;  // wave-uniform
#pragma unroll
        for (int o = 0; o < 64; ++o) acc[o] = fmaf(val, wp[o], acc[o]);
      }
    }
  }
#pragma unroll
  for (int o = 0; o < 64; ++o)
    atomicAdd(&out[((b * 64 + o) * HH + h) * WW + w], acc[o]);
}

// ---------------------------------------------------------------------------
// BN stats, x4 split: block = (b*64+o)*4 + quarter. double accumulate, LDS
// reduce, 2 f64 atomics per block. grid 1024 -> 4 blocks/CU.
// ---------------------------------------------------------------------------
__global__ __launch_bounds__(256) void bnstats_kernel(
    const float* __restrict__ out, double* __restrict__ sums) {
  const int bo = blockIdx.x >> 2;      // b*64+o
  const int q = blockIdx.x & 3;
  const int o = bo & 63;
  const float4* p = (const float4*)(out + bo * HWD + q * (HWD / 4));
  double s = 0.0, s2 = 0.0;
  for (int i = threadIdx.x; i < HWD / 16; i += 256) {
    float4 v = p[i];
    s += (double)v.x + (double)v.y + (double)v.z + (double)v.w;
    s2 += (double)v.x * v.x + (double)v.y * v.y +
          (double)v.z * v.z + (double)v.w * v.w;
  }
  __shared__ double sh[2][256];
  sh[0][threadIdx.x] = s;
  sh[1][threadIdx.x] = s2;
  __syncthreads();
  for (int t = 128; t > 0; t >>= 1) {
    if (threadIdx.x < t) {
      sh[0][threadIdx.x] += sh[0][threadIdx.x + t];
      sh[1][threadIdx.x] += sh[1][threadIdx.x + t];
    }
    __syncthreads();
  }
  if (threadIdx.x == 0) {
    atomicAdd(&sums[o], sh[0][0]);
    atomicAdd(&sums[64 + o], sh[1][0]);
  }
}

// ---------------------------------------------------------------------------
// BN apply + ReLU, in place on d_out's conv region (float4 vectorized).
// ---------------------------------------------------------------------------
__global__ __launch_bounds__(256) void bnapply_kernel(
    float* __restrict__ out, const double* __restrict__ sums,
    const float* __restrict__ gamma, const float* __restrict__ beta) {
  const int i = blockIdx.x * 256 + threadIdx.x;  // over OUT_ELEMS/4
  if (i >= OUT_ELEMS / 4) return;
  const int o = (i / (HWD / 4)) & 63;
  const float n_inv = 1.0f / (float)(BB * HWD);
  float mean = (float)sums[o] * n_inv;
  float var = (float)sums[64 + o] * n_inv - mean * mean;
  float inv = gamma[o] * rsqrtf(var + EPSBN);
  float bt = beta[o];
  float4 v = ((float4*)out)[i];
  v.x = fmaxf(0.f, (v.x - mean) * inv + bt);
  v.y = fmaxf(0.f, (v.y - mean) * inv + bt);
  v.z = fmaxf(0.f, (v.z - mean) * inv + bt);
  v.w = fmaxf(0.f, (v.w - mean) * inv + bt);
  ((float4*)out)[i] = v;
}

extern "C" void kernel_launch(void* const* d_in, const int* in_sizes, int n_in,
                              void* d_out, int out_size, void* d_ws, size_t ws_size,
                              hipStream_t stream) {
  const float* x = (const float*)d_in[0];      // [4,64,160,160]
  const float* d = (const float*)d_in[1];      // [4,64,160,160]
  const float* ow = (const float*)d_in[2];     // [18,64,3,3]
  const float* cw = (const float*)d_in[3];     // [64,64,3,3]
  const float* gamma = (const float*)d_in[4];  // [64]
  const float* beta = (const float*)d_in[5];   // [64]

  float* out = (float*)d_out;                  // conv/BN output, 6,553,600 f32
  float* off_out = out + OUT_ELEMS;            // clamped offsets, 1,843,200 f32

  // workspace: wct (36864 f) | wot (10368 f) | sums (128 doubles, 8B-aligned)
  float* wct = (float*)d_ws;
  float* wot = wct + 36864;
  double* sums = (double*)(wot + 10368);       // byte offset 188928, %8==0

  // zero-init both output regions (atomic accumulation targets)
  hipMemsetAsync(d_out, 0, (size_t)(OUT_ELEMS + OFF_ELEMS) * 4, stream);

  prep_kernel<<<144, 256, 0, stream>>>(cw, ow, wct, wot, sums);

  dim3 tiles(WW / 16, HH / 16, BB * 4);        // 10x10x16 = 1600 blocks
  offconv_kernel<<<tiles, 256, 0, stream>>>(d, wot, off_out);
  clamp_kernel<<<(OFF_ELEMS / 4 + 255) / 256, 256, 0, stream>>>(off_out);
  dconv_kernel<<<tiles, 256, 0, stream>>>(x, off_out, wct, out);

  bnstats_kernel<<<BB * COUT * 4, 256, 0, stream>>>(out, sums);
  bnapply_kernel<<<(OUT_ELEMS / 4 + 255) / 256, 256, 0, stream>>>(
      out, sums, gamma, beta);
}

// Round 3
// 259.063 us; speedup vs baseline: 1.5925x; 1.5925x over previous
//
#include <hip/hip_runtime.h>
#include <hip/hip_bf16.h>

#define BB 4
#define HH 160
#define WW 160
#define HWD (HH * WW)                   // 25600
#define OUT_ELEMS (BB * 64 * HWD)       // 6,553,600
#define OFF_ELEMS (BB * 18 * HWD)       // 1,843,200
#define EPSBN 1e-5f

typedef __attribute__((ext_vector_type(8))) short bf16x8;
typedef __attribute__((ext_vector_type(4))) float f32x4;

__device__ inline unsigned pack2bf(float a, float b) {
  __hip_bfloat162 h2 = __float22bfloat162_rn(float2{a, b});
  unsigned u;
  __builtin_memcpy(&u, &h2, 4);
  return u;
}
__device__ inline unsigned short bf16bits(float a) {
  __hip_bfloat16 h = __float2bfloat16(a);
  unsigned short u;
  __builtin_memcpy(&u, &h, 2);
  return u;
}

// ---------------------------------------------------------------------------
// prep: build per-lane prepacked MFMA B-fragments for dconv (Bp) and offconv
// (B2p), bf16, K padded 72->96 per 8-ch chunk (pad rows ZERO so garbage A pad
// cols would still need zeroing -- we zero those too), and zero BN sums.
// Bp[nt(4)][ki(24)][lane(64)][j(8)]: B[k = ki*32+(l>>4)*8+j][n = nt*16+(l&15)]
// ---------------------------------------------------------------------------
__global__ void prep_kernel(const float* __restrict__ cw,
                            const float* __restrict__ ow,
                            unsigned short* __restrict__ Bp,
                            unsigned short* __restrict__ B2p,
                            double* __restrict__ sums) {
  int i = blockIdx.x * 256 + threadIdx.x;
  if (i < 128) sums[i] = 0.0;
  if (i < 49152) {                      // dconv weights conv_w[o=n][c][t]
    int j = i & 7, l = (i >> 3) & 63, rest = i >> 9;
    int ki = rest % 24, nt = rest / 24;
    int kp = ki * 32 + ((l >> 4) << 3) + j;
    int chunk = kp / 96, kq = kp % 96;
    int n = nt * 16 + (l & 15);
    float v = 0.f;
    if (kq < 72) v = cw[n * 576 + (chunk * 8 + kq / 9) * 9 + kq % 9];
    Bp[i] = bf16bits(v);
  }
  if (i < 24576) {                      // offconv weights offset_w[o=n][c][t]
    int j = i & 7, l = (i >> 3) & 63, rest = i >> 9;
    int ki = rest % 24, nt = rest / 24;
    int kp = ki * 32 + ((l >> 4) << 3) + j;
    int chunk = kp / 96, kq = kp % 96;
    int n = nt * 16 + (l & 15);
    float v = 0.f;
    if (kq < 72 && n < 18) v = ow[n * 576 + (chunk * 8 + kq / 9) * 9 + kq % 9];
    B2p[i] = bf16bits(v);
  }
}

// ---------------------------------------------------------------------------
// offconv as implicit GEMM: M=128 (16x8 tile), N=18 (padded 32), K=576
// (8 chunks of 72 padded 96). A2 = im2col of d staged via LDS patch.
// 4 waves: wave w -> n-tile (w>>1), m-half (w&1). Clamped fp32 offsets out.
// ---------------------------------------------------------------------------
__global__ __launch_bounds__(256) void offconv_kernel(
    const float* __restrict__ d, const bf16x8* __restrict__ B2p,
    float* __restrict__ off_out) {
  const int b = blockIdx.z;
  const int tx0 = blockIdx.x * 16, ty0 = blockIdx.y * 8;
  const int tid = threadIdx.x;
  const int lane = tid & 63, wv = tid >> 6;
  const int p = tid & 127, cg = tid >> 7;
  const int px = p & 15, py = p >> 4;

  __shared__ float patch[8 * 180];            // 8 ch x 10 x 18
  __shared__ unsigned short Abuf[128 * 104];  // row stride 104 (bank-safe)

  if (tid < 128) {                            // zero K-pad cols [72,96)
    uint2 z{0u, 0u};
    uint2* zp = (uint2*)(Abuf + tid * 104 + 72);
#pragma unroll
    for (int i = 0; i < 6; ++i) zp[i] = z;
  }

  f32x4 acc[4];
#pragma unroll
  for (int i = 0; i < 4; ++i) acc[i] = f32x4{0.f, 0.f, 0.f, 0.f};
  const int nt = wv >> 1, mh = wv & 1;

  for (int chunk = 0; chunk < 8; ++chunk) {
    bf16x8 bf[3];
#pragma unroll
    for (int kk = 0; kk < 3; ++kk)
      bf[kk] = B2p[(nt * 24 + chunk * 3 + kk) * 64 + lane];
    __syncthreads();                          // prev MFMA done reading Abuf
    for (int l = tid; l < 1440; l += 256) {   // stage 8ch x 10 x 18
      int c = l / 180, rc = l % 180, r = rc / 18, col = rc % 18;
      int gy = ty0 - 1 + r, gx = tx0 - 1 + col;
      float v = 0.f;
      if (gy >= 0 && gy < HH && gx >= 0 && gx < WW)
        v = d[((b * 64 + chunk * 8 + c) * HH + gy) * WW + gx];
      patch[l] = v;
    }
    __syncthreads();                          // patch ready
#pragma unroll
    for (int half = 0; half < 2; ++half) {    // 2 channels per half
      float vals[18];
#pragma unroll
      for (int cl = 0; cl < 2; ++cl) {
        const float* q = patch + (cg * 4 + half * 2 + cl) * 180;
#pragma unroll
        for (int k = 0; k < 9; ++k)
          vals[cl * 9 + k] = q[(py + k / 3) * 18 + px + k % 3];
      }
      unsigned* arow = (unsigned*)(Abuf + p * 104 + cg * 36 + half * 18);
#pragma unroll
      for (int i = 0; i < 9; ++i)
        arow[i] = pack2bf(vals[2 * i], vals[2 * i + 1]);
    }
    __syncthreads();                          // A ready
#pragma unroll
    for (int kk = 0; kk < 3; ++kk) {
#pragma unroll
      for (int mf = 0; mf < 4; ++mf) {
        const bf16x8* ap = (const bf16x8*)(
            Abuf + (mh * 64 + mf * 16 + (lane & 15)) * 104 +
            kk * 32 + (lane >> 4) * 8);
        acc[mf] = __builtin_amdgcn_mfma_f32_16x16x32_bf16(*ap, bf[kk],
                                                          acc[mf], 0, 0, 0);
      }
    }
  }
  // epilogue: C row m = (lane>>4)*4+reg, col n = lane&15 ; clamp, store
  const int n = nt * 16 + (lane & 15);
  if (n < 18) {
#pragma unroll
    for (int mf = 0; mf < 4; ++mf)
#pragma unroll
      for (int r = 0; r < 4; ++r) {
        int m = mh * 64 + mf * 16 + (lane >> 4) * 4 + r;
        float v = fminf(1.f, fmaxf(-1.f, acc[mf][r]));
        off_out[((b * 18 + n) * HH + ty0 + (m >> 4)) * WW + tx0 + (m & 15)] = v;
      }
  }
}

// ---------------------------------------------------------------------------
// deformable conv as implicit GEMM: M=128 (16x8 tile), N=64, K=576 padded 768.
// Per chunk: stage 21x13 fp32 patch (offsets clamped to [-1,1] => all
// bilinear corners inside, zero-fill == reference zero-pad), interp -> bf16
// A-tile, 3 k-iters of mfma 16x16x32. Wave w owns n-tile w, all 8 m-frags.
// ---------------------------------------------------------------------------
__global__ __launch_bounds__(256) void dconv_kernel(
    const float* __restrict__ x, const float* __restrict__ offs,
    const bf16x8* __restrict__ Bp, float* __restrict__ out) {
  const int b = blockIdx.z;
  const int tx0 = blockIdx.x * 16, ty0 = blockIdx.y * 8;
  const int tid = threadIdx.x;
  const int lane = tid & 63, wv = tid >> 6;
  const int p = tid & 127, cg = tid >> 7;
  const int px = p & 15, py = p >> 4;
  const int h = ty0 + py, w = tx0 + px;

  __shared__ float patch[8 * 273];            // 8 ch x 13 x 21
  __shared__ unsigned short Abuf[128 * 104];

  // bilinear setup per tap (clamp guarantee: ry in [0,11], rx in [0,19])
  int bse[9];
  float w00[9], w01[9], w10[9], w11[9];
#pragma unroll
  for (int k = 0; k < 9; ++k) {
    float dy = offs[((b * 18 + 2 * k) * HH + h) * WW + w];
    float dx = offs[((b * 18 + 2 * k + 1) * HH + h) * WW + w];
    float pyf = (float)(h - 1 + k / 3) + dy;
    float pxf = (float)(w - 1 + k % 3) + dx;
    float y0 = floorf(pyf), x0 = floorf(pxf);
    float wy = pyf - y0, wx = pxf - x0;
    bse[k] = ((int)y0 - (ty0 - 2)) * 21 + ((int)x0 - (tx0 - 2));
    w00[k] = (1.f - wy) * (1.f - wx);
    w01[k] = (1.f - wy) * wx;
    w10[k] = wy * (1.f - wx);
    w11[k] = wy * wx;
  }

  if (tid < 128) {                            // zero K-pad cols [72,96)
    uint2 z{0u, 0u};
    uint2* zp = (uint2*)(Abuf + tid * 104 + 72);
#pragma unroll
    for (int i = 0; i < 6; ++i) zp[i] = z;
  }

  f32x4 acc[8];
#pragma unroll
  for (int i = 0; i < 8; ++i) acc[i] = f32x4{0.f, 0.f, 0.f, 0.f};
  const int nt = wv;

  for (int chunk = 0; chunk < 8; ++chunk) {
    bf16x8 bf[3];
#pragma unroll
    for (int kk = 0; kk < 3; ++kk)
      bf[kk] = Bp[(nt * 24 + chunk * 3 + kk) * 64 + lane];
    __syncthreads();                          // prev MFMA done reading Abuf
    for (int l = tid; l < 2184; l += 256) {   // stage 8ch x 13 x 21
      int c = l / 273, rc = l % 273, r = rc / 21, col = rc % 21;
      int gy = ty0 - 2 + r, gx = tx0 - 2 + col;
      float v = 0.f;
      if (gy >= 0 && gy < HH && gx >= 0 && gx < WW)
        v = x[((b * 64 + chunk * 8 + c) * HH + gy) * WW + gx];
      patch[l] = v;
    }
    __syncthreads();                          // patch ready
#pragma unroll
    for (int half = 0; half < 2; ++half) {    // 2 channels per half
      float vals[18];
#pragma unroll
      for (int cl = 0; cl < 2; ++cl) {
        const float* q = patch + (cg * 4 + half * 2 + cl) * 273;
#pragma unroll
        for (int k = 0; k < 9; ++k) {
          int bs = bse[k];
          vals[cl * 9 + k] = w00[k] * q[bs] + w01[k] * q[bs + 1] +
                             w10[k] * q[bs + 21] + w11[k] * q[bs + 22];
        }
      }
      unsigned* arow = (unsigned*)(Abuf + p * 104 + cg * 36 + half * 18);
#pragma unroll
      for (int i = 0; i < 9; ++i)
        arow[i] = pack2bf(vals[2 * i], vals[2 * i + 1]);
    }
    __syncthreads();                          // A ready
#pragma unroll
    for (int kk = 0; kk < 3; ++kk) {
#pragma unroll
      for (int mf = 0; mf < 8; ++mf) {
        const bf16x8* ap = (const bf16x8*)(
            Abuf + (mf * 16 + (lane & 15)) * 104 + kk * 32 + (lane >> 4) * 8);
        acc[mf] = __builtin_amdgcn_mfma_f32_16x16x32_bf16(*ap, bf[kk],
                                                          acc[mf], 0, 0, 0);
      }
    }
  }
  // epilogue: C row m=(lane>>4)*4+reg, col n=lane&15 -> out[b][n][h][w]
  const int n = nt * 16 + (lane & 15);
#pragma unroll
  for (int mf = 0; mf < 8; ++mf)
#pragma unroll
    for (int r = 0; r < 4; ++r) {
      int m = mf * 16 + (lane >> 4) * 4 + r;
      out[((b * 64 + n) * HH + ty0 + (m >> 4)) * WW + tx0 + (m & 15)] =
          acc[mf][r];
    }
}

// ---------------------------------------------------------------------------
// BN stats, x4 split: block = (b*64+o)*4 + quarter; f64 block-reduce + atomics
// ---------------------------------------------------------------------------
__global__ __launch_bounds__(256) void bnstats_kernel(
    const float* __restrict__ out, double* __restrict__ sums) {
  const int bo = blockIdx.x >> 2;
  const int q = blockIdx.x & 3;
  const int o = bo & 63;
  const float4* p = (const float4*)(out + bo * HWD + q * (HWD / 4));
  double s = 0.0, s2 = 0.0;
  for (int i = threadIdx.x; i < HWD / 16; i += 256) {
    float4 v = p[i];
    s += (double)v.x + (double)v.y + (double)v.z + (double)v.w;
    s2 += (double)v.x * v.x + (double)v.y * v.y +
          (double)v.z * v.z + (double)v.w * v.w;
  }
  __shared__ double sh[2][256];
  sh[0][threadIdx.x] = s;
  sh[1][threadIdx.x] = s2;
  __syncthreads();
  for (int t = 128; t > 0; t >>= 1) {
    if (threadIdx.x < t) {
      sh[0][threadIdx.x] += sh[0][threadIdx.x + t];
      sh[1][threadIdx.x] += sh[1][threadIdx.x + t];
    }
    __syncthreads();
  }
  if (threadIdx.x == 0) {
    atomicAdd(&sums[o], sh[0][0]);
    atomicAdd(&sums[64 + o], sh[1][0]);
  }
}

__global__ __launch_bounds__(256) void bnapply_kernel(
    float* __restrict__ out, const double* __restrict__ sums,
    const float* __restrict__ gamma, const float* __restrict__ beta) {
  const int i = blockIdx.x * 256 + threadIdx.x;
  if (i >= OUT_ELEMS / 4) return;
  const int o = (i / (HWD / 4)) & 63;
  const float n_inv = 1.0f / (float)(BB * HWD);
  float mean = (float)sums[o] * n_inv;
  float var = (float)sums[64 + o] * n_inv - mean * mean;
  float inv = gamma[o] * rsqrtf(var + EPSBN);
  float bt = beta[o];
  float4 v = ((float4*)out)[i];
  v.x = fmaxf(0.f, (v.x - mean) * inv + bt);
  v.y = fmaxf(0.f, (v.y - mean) * inv + bt);
  v.z = fmaxf(0.f, (v.z - mean) * inv + bt);
  v.w = fmaxf(0.f, (v.w - mean) * inv + bt);
  ((float4*)out)[i] = v;
}

extern "C" void kernel_launch(void* const* d_in, const int* in_sizes, int n_in,
                              void* d_out, int out_size, void* d_ws, size_t ws_size,
                              hipStream_t stream) {
  const float* x = (const float*)d_in[0];
  const float* d = (const float*)d_in[1];
  const float* ow = (const float*)d_in[2];
  const float* cw = (const float*)d_in[3];
  const float* gamma = (const float*)d_in[4];
  const float* beta = (const float*)d_in[5];

  float* out = (float*)d_out;
  float* off_out = out + OUT_ELEMS;

  // ws: sums double[128] | Bp ushort[49152] | B2p ushort[24576]
  double* sums = (double*)d_ws;
  unsigned short* Bp = (unsigned short*)((char*)d_ws + 1024);
  unsigned short* B2p = Bp + 49152;

  prep_kernel<<<192, 256, 0, stream>>>(cw, ow, Bp, B2p, sums);

  dim3 tiles(WW / 16, HH / 8, BB);            // 10 x 20 x 4 = 800 blocks
  offconv_kernel<<<tiles, 256, 0, stream>>>(d, (const bf16x8*)B2p, off_out);
  dconv_kernel<<<tiles, 256, 0, stream>>>(x, off_out, (const bf16x8*)Bp, out);

  bnstats_kernel<<<BB * 64 * 4, 256, 0, stream>>>(out, sums);
  bnapply_kernel<<<(OUT_ELEMS / 4 + 255) / 256, 256, 0, stream>>>(
      out, sums, gamma, beta);
}

// Round 4
// 183.641 us; speedup vs baseline: 2.2465x; 1.4107x over previous
//
#include <hip/hip_runtime.h>
#include <hip/hip_bf16.h>

#define BB 4
#define HH 160
#define WW 160
#define HWD (HH * WW)                   // 25600
#define OUT_ELEMS (BB * 64 * HWD)       // 6,553,600
#define OFF_ELEMS (BB * 18 * HWD)       // 1,843,200
#define EPSBN 1e-5f
#define CHSTRIDE (8 * HWD)              // 8-channel chunk stride

typedef __attribute__((ext_vector_type(8))) short bf16x8;
typedef __attribute__((ext_vector_type(4))) float f32x4;

__device__ inline unsigned pack2bf(float a, float b) {
  __hip_bfloat162 h2 = __float22bfloat162_rn(float2{a, b});
  unsigned u;
  __builtin_memcpy(&u, &h2, 4);
  return u;
}
__device__ inline unsigned short bf16bits(float a) {
  __hip_bfloat16 h = __float2bfloat16(a);
  unsigned short u;
  __builtin_memcpy(&u, &h, 2);
  return u;
}

// ---------------------------------------------------------------------------
// prep: prepacked MFMA B-fragments, K-order PERMUTED to kappa = tap*8 + ch
// within each 8-channel chunk (96-padded: taps 9..11 are zero rows).
// Bp[nt][ki=chunk*3+kk][lane][j]: B[kappa = kk*32+(l>>4)*8+j][n = nt*16+(l&15)]
// with tap t = kappa>>3, ch c = kappa&7.
// ---------------------------------------------------------------------------
__global__ void prep_kernel(const float* __restrict__ cw,
                            const float* __restrict__ ow,
                            unsigned short* __restrict__ Bp,
                            unsigned short* __restrict__ B2p,
                            double* __restrict__ sums) {
  int i = blockIdx.x * 256 + threadIdx.x;
  if (i < 128) sums[i] = 0.0;
  if (i < 49152) {                      // dconv weights conv_w[n][c][t], nt 0..3
    int j = i & 7, l = (i >> 3) & 63, rest = i >> 9;
    int ki = rest % 24, nt = rest / 24;
    int kp = ki * 32 + ((l >> 4) << 3) + j;
    int chunk = kp / 96, kq = kp % 96;
    int t = kq >> 3, c = kq & 7;
    int n = nt * 16 + (l & 15);
    float v = (t < 9) ? cw[n * 576 + (chunk * 8 + c) * 9 + t] : 0.f;
    Bp[i] = bf16bits(v);
  }
  if (i < 24576) {                      // offconv weights, nt 0..1, n<18
    int j = i & 7, l = (i >> 3) & 63, rest = i >> 9;
    int ki = rest % 24, nt = rest / 24;
    int kp = ki * 32 + ((l >> 4) << 3) + j;
    int chunk = kp / 96, kq = kp % 96;
    int t = kq >> 3, c = kq & 7;
    int n = nt * 16 + (l & 15);
    float v = (t < 9 && n < 18) ? ow[n * 576 + (chunk * 8 + c) * 9 + t] : 0.f;
    B2p[i] = bf16bits(v);
  }
}

// ---------------------------------------------------------------------------
// offconv implicit GEMM, M=64 (16x4 tile), N=32 (18 used), K=576 pad 768.
// Thread (wv,lane): pixel m = wv*16+(lane&15); owns A-cells (mf=wv, kk=0..2,
// lane): octet = tap t=kk*4+(lane>>4), 8 channels -> one ds_write_b128 into
// fragment order. MFMA: wave wv -> nt=wv>>1, mf in {2*(wv&1), 2*(wv&1)+1}.
// ---------------------------------------------------------------------------
__global__ __launch_bounds__(256) void offconv_kernel(
    const float* __restrict__ d, const bf16x8* __restrict__ B2p,
    float* __restrict__ off_out) {
  const int b = blockIdx.z;
  const int tx0 = blockIdx.x * 16, ty0 = blockIdx.y * 4;
  const int tid = threadIdx.x;
  const int wv = tid >> 6, lane = tid & 63;
  const int lo = lane >> 4, li = lane & 15;
  const int px = li, py = wv;

  __shared__ float p2[864];            // 8 ch x 6 rows x 18 cols
  __shared__ bf16x8 Af[768];           // [mf*3+kk][lane]

  // tap sample offsets (t = kk*4+lo; direct 3x3 sampling, row0 = ty0-1)
  int poff[3];
  bool tre[3];
#pragma unroll
  for (int kk = 0; kk < 3; ++kk) {
    int t = kk * 4 + lo;
    tre[kk] = (t < 9);
    poff[kk] = tre[kk] ? ((py + t / 3) * 18 + px + t % 3) : 0;
  }

  // staging descriptors (4 slots)
  int goff[4];
  bool gok[4];
#pragma unroll
  for (int i = 0; i < 4; ++i) {
    int l = tid + i * 256;
    int c = l / 108, rc = l % 108, r = rc / 18, col = rc % 18;
    int gy = ty0 - 1 + r, gx = tx0 - 1 + col;
    gok[i] = (l < 864) && gy >= 0 && gy < HH && gx >= 0 && gx < WW;
    goff[i] = ((b * 64 + c) * HH + gy) * WW + gx;
  }
  float g[4];
#pragma unroll
  for (int i = 0; i < 4; ++i) g[i] = gok[i] ? d[goff[i]] : 0.f;

  f32x4 acc0{0.f, 0.f, 0.f, 0.f}, acc1{0.f, 0.f, 0.f, 0.f};
  const int nt = wv >> 1, mh = wv & 1;

  for (int chunk = 0; chunk < 8; ++chunk) {
    bf16x8 bw0 = B2p[((nt * 24 + chunk * 3 + 0) << 6) + lane];
    bf16x8 bw1 = B2p[((nt * 24 + chunk * 3 + 1) << 6) + lane];
    bf16x8 bw2 = B2p[((nt * 24 + chunk * 3 + 2) << 6) + lane];
#pragma unroll
    for (int i = 0; i < 4; ++i) {
      int l = tid + i * 256;
      if (l < 864) p2[l] = g[i];
    }
    __syncthreads();
    int nco = ((chunk < 7) ? (chunk + 1) : 7) * CHSTRIDE;   // prefetch next
#pragma unroll
    for (int i = 0; i < 4; ++i) g[i] = gok[i] ? d[goff[i] + nco] : 0.f;
#pragma unroll
    for (int kk = 0; kk < 3; ++kk) {
      union { bf16x8 v; unsigned u[4]; } a;
      if (tre[kk]) {
        const float* q = p2 + poff[kk];
#pragma unroll
        for (int j = 0; j < 4; ++j)
          a.u[j] = pack2bf(q[(2 * j) * 108], q[(2 * j + 1) * 108]);
      } else {
        a.u[0] = a.u[1] = a.u[2] = a.u[3] = 0u;
      }
      Af[((wv * 3 + kk) << 6) + lane] = a.v;
    }
    __syncthreads();
#pragma unroll
    for (int kk = 0; kk < 3; ++kk) {
      bf16x8 bw = (kk == 0) ? bw0 : (kk == 1) ? bw1 : bw2;
      acc0 = __builtin_amdgcn_mfma_f32_16x16x32_bf16(
          Af[(((mh * 2) * 3 + kk) << 6) + lane], bw, acc0, 0, 0, 0);
      acc1 = __builtin_amdgcn_mfma_f32_16x16x32_bf16(
          Af[(((mh * 2 + 1) * 3 + kk) << 6) + lane], bw, acc1, 0, 0, 0);
    }
  }
  // epilogue: m = mf*16 + lo*4 + r -> row ty0+mf, col tx0+lo*4+r; clamp
  const int n = nt * 16 + li;
  if (n < 18) {
#pragma unroll
    for (int f = 0; f < 2; ++f) {
      int mf = mh * 2 + f;
      f32x4 a = f ? acc1 : acc0;
      float* po = off_out + ((b * 18 + n) * HH + ty0 + mf) * WW + tx0 + lo * 4;
      float4 v;
      v.x = fminf(1.f, fmaxf(-1.f, a[0]));
      v.y = fminf(1.f, fmaxf(-1.f, a[1]));
      v.z = fminf(1.f, fmaxf(-1.f, a[2]));
      v.w = fminf(1.f, fmaxf(-1.f, a[3]));
      *(float4*)po = v;
    }
  }
}

// ---------------------------------------------------------------------------
// dconv implicit GEMM, M=64 (16x4), N=64, K=576 pad 768, grid 1600.
// Same fragment-direct A layout; octet = one bilinear tap x 8 channels.
// Offsets clamped to [-1,1] => corners inside 9x21 zero-padded patch.
// ---------------------------------------------------------------------------
__global__ __launch_bounds__(256) void dconv_kernel(
    const float* __restrict__ x, const float* __restrict__ offs,
    const bf16x8* __restrict__ Bp, float* __restrict__ out) {
  const int b = blockIdx.z;
  const int tx0 = blockIdx.x * 16, ty0 = blockIdx.y * 4;
  const int tid = threadIdx.x;
  const int wv = tid >> 6, lane = tid & 63;
  const int lo = lane >> 4, li = lane & 15;
  const int px = li, py = wv;
  const int h = ty0 + py, w = tx0 + px;

  __shared__ float patch[1512];        // 8 ch x 9 rows x 21 cols
  __shared__ bf16x8 Af[768];

  // bilinear setup for this thread's taps (t = kk*4+lo)
  int bs[3];
  float W00[3], W01[3], W10[3], W11[3];
  bool tre[3];
#pragma unroll
  for (int kk = 0; kk < 3; ++kk) {
    int t = kk * 4 + lo;
    tre[kk] = (t < 9);
    if (tre[kk]) {
      float dy = offs[((b * 18 + 2 * t) * HH + h) * WW + w];
      float dx = offs[((b * 18 + 2 * t + 1) * HH + h) * WW + w];
      float pyf = (float)(h - 1 + t / 3) + dy;
      float pxf = (float)(w - 1 + t % 3) + dx;
      float y0 = floorf(pyf), x0 = floorf(pxf);
      float wy = pyf - y0, wx = pxf - x0;
      bs[kk] = ((int)y0 - (ty0 - 2)) * 21 + ((int)x0 - (tx0 - 2));
      W00[kk] = (1.f - wy) * (1.f - wx);
      W01[kk] = (1.f - wy) * wx;
      W10[kk] = wy * (1.f - wx);
      W11[kk] = wy * wx;
    } else {
      bs[kk] = 0;
      W00[kk] = W01[kk] = W10[kk] = W11[kk] = 0.f;
    }
  }

  // staging descriptors (6 slots)
  int goff[6];
  bool gok[6];
#pragma unroll
  for (int i = 0; i < 6; ++i) {
    int l = tid + i * 256;
    int c = l / 189, rc = l % 189, r = rc / 21, col = rc % 21;
    int gy = ty0 - 2 + r, gx = tx0 - 2 + col;
    gok[i] = (l < 1512) && gy >= 0 && gy < HH && gx >= 0 && gx < WW;
    goff[i] = ((b * 64 + c) * HH + gy) * WW + gx;
  }
  float g[6];
#pragma unroll
  for (int i = 0; i < 6; ++i) g[i] = gok[i] ? x[goff[i]] : 0.f;

  f32x4 acc[4];
#pragma unroll
  for (int i = 0; i < 4; ++i) acc[i] = f32x4{0.f, 0.f, 0.f, 0.f};
  const int nt = wv;

  for (int chunk = 0; chunk < 8; ++chunk) {
    bf16x8 bw0 = Bp[((nt * 24 + chunk * 3 + 0) << 6) + lane];
    bf16x8 bw1 = Bp[((nt * 24 + chunk * 3 + 1) << 6) + lane];
    bf16x8 bw2 = Bp[((nt * 24 + chunk * 3 + 2) << 6) + lane];
#pragma unroll
    for (int i = 0; i < 6; ++i) {
      int l = tid + i * 256;
      if (l < 1512) patch[l] = g[i];
    }
    __syncthreads();
    int nco = ((chunk < 7) ? (chunk + 1) : 7) * CHSTRIDE;   // prefetch next
#pragma unroll
    for (int i = 0; i < 6; ++i) g[i] = gok[i] ? x[goff[i] + nco] : 0.f;
#pragma unroll
    for (int kk = 0; kk < 3; ++kk) {
      union { bf16x8 v; unsigned u[4]; } a;
      if (tre[kk]) {
        const float* q = patch + bs[kk];
        float v[8];
#pragma unroll
        for (int j = 0; j < 8; ++j) {
          const float* pc = q + j * 189;
          v[j] = W00[kk] * pc[0] + W01[kk] * pc[1] +
                 W10[kk] * pc[21] + W11[kk] * pc[22];
        }
#pragma unroll
        for (int j = 0; j < 4; ++j)
          a.u[j] = pack2bf(v[2 * j], v[2 * j + 1]);
      } else {
        a.u[0] = a.u[1] = a.u[2] = a.u[3] = 0u;
      }
      Af[((wv * 3 + kk) << 6) + lane] = a.v;
    }
    __syncthreads();
#pragma unroll
    for (int kk = 0; kk < 3; ++kk) {
      bf16x8 bw = (kk == 0) ? bw0 : (kk == 1) ? bw1 : bw2;
#pragma unroll
      for (int mf = 0; mf < 4; ++mf)
        acc[mf] = __builtin_amdgcn_mfma_f32_16x16x32_bf16(
            Af[((mf * 3 + kk) << 6) + lane], bw, acc[mf], 0, 0, 0);
    }
  }
  // epilogue: aligned float4 stores (full 64B lines per instruction)
  const int n = nt * 16 + li;
#pragma unroll
  for (int mf = 0; mf < 4; ++mf) {
    float* po = out + ((b * 64 + n) * HH + ty0 + mf) * WW + tx0 + lo * 4;
    *(float4*)po = make_float4(acc[mf][0], acc[mf][1], acc[mf][2], acc[mf][3]);
  }
}

// ---------------------------------------------------------------------------
// BN stats, x4 split; f64 block-reduce + atomics.
// ---------------------------------------------------------------------------
__global__ __launch_bounds__(256) void bnstats_kernel(
    const float* __restrict__ out, double* __restrict__ sums) {
  const int bo = blockIdx.x >> 2;
  const int q = blockIdx.x & 3;
  const int o = bo & 63;
  const float4* p = (const float4*)(out + bo * HWD + q * (HWD / 4));
  double s = 0.0, s2 = 0.0;
  for (int i = threadIdx.x; i < HWD / 16; i += 256) {
    float4 v = p[i];
    s += (double)v.x + (double)v.y + (double)v.z + (double)v.w;
    s2 += (double)v.x * v.x + (double)v.y * v.y +
          (double)v.z * v.z + (double)v.w * v.w;
  }
  __shared__ double sh[2][256];
  sh[0][threadIdx.x] = s;
  sh[1][threadIdx.x] = s2;
  __syncthreads();
  for (int t = 128; t > 0; t >>= 1) {
    if (threadIdx.x < t) {
      sh[0][threadIdx.x] += sh[0][threadIdx.x + t];
      sh[1][threadIdx.x] += sh[1][threadIdx.x + t];
    }
    __syncthreads();
  }
  if (threadIdx.x == 0) {
    atomicAdd(&sums[o], sh[0][0]);
    atomicAdd(&sums[64 + o], sh[1][0]);
  }
}

__global__ __launch_bounds__(256) void bnapply_kernel(
    float* __restrict__ out, const double* __restrict__ sums,
    const float* __restrict__ gamma, const float* __restrict__ beta) {
  const int i = blockIdx.x * 256 + threadIdx.x;
  if (i >= OUT_ELEMS / 4) return;
  const int o = (i / (HWD / 4)) & 63;
  const float n_inv = 1.0f / (float)(BB * HWD);
  float mean = (float)sums[o] * n_inv;
  float var = (float)sums[64 + o] * n_inv - mean * mean;
  float inv = gamma[o] * rsqrtf(var + EPSBN);
  float bt = beta[o];
  float4 v = ((float4*)out)[i];
  v.x = fmaxf(0.f, (v.x - mean) * inv + bt);
  v.y = fmaxf(0.f, (v.y - mean) * inv + bt);
  v.z = fmaxf(0.f, (v.z - mean) * inv + bt);
  v.w = fmaxf(0.f, (v.w - mean) * inv + bt);
  ((float4*)out)[i] = v;
}

extern "C" void kernel_launch(void* const* d_in, const int* in_sizes, int n_in,
                              void* d_out, int out_size, void* d_ws, size_t ws_size,
                              hipStream_t stream) {
  const float* x = (const float*)d_in[0];
  const float* d = (const float*)d_in[1];
  const float* ow = (const float*)d_in[2];
  const float* cw = (const float*)d_in[3];
  const float* gamma = (const float*)d_in[4];
  const float* beta = (const float*)d_in[5];

  float* out = (float*)d_out;
  float* off_out = out + OUT_ELEMS;

  // ws: sums double[128] | Bp ushort[49152] | B2p ushort[24576]
  double* sums = (double*)d_ws;
  unsigned short* Bp = (unsigned short*)((char*)d_ws + 1024);
  unsigned short* B2p = Bp + 49152;

  prep_kernel<<<192, 256, 0, stream>>>(cw, ow, Bp, B2p, sums);

  dim3 tiles(WW / 16, HH / 4, BB);            // 10 x 40 x 4 = 1600 blocks
  offconv_kernel<<<tiles, 256, 0, stream>>>(d, (const bf16x8*)B2p, off_out);
  dconv_kernel<<<tiles, 256, 0, stream>>>(x, off_out, (const bf16x8*)Bp, out);

  bnstats_kernel<<<BB * 64 * 4, 256, 0, stream>>>(out, sums);
  bnapply_kernel<<<(OUT_ELEMS / 4 + 255) / 256, 256, 0, stream>>>(
      out, sums, gamma, beta);
}

// Round 5
// 164.430 us; speedup vs baseline: 2.5090x; 1.1168x over previous
//
#include <hip/hip_runtime.h>
#include <hip/hip_bf16.h>

#define BB 4
#define HH 160
#define WW 160
#define HWD (HH * WW)                   // 25600
#define OUT_ELEMS (BB * 64 * HWD)       // 6,553,600
#define OFF_ELEMS (BB * 18 * HWD)       // 1,843,200
#define EPSBN 1e-5f
#define CHSTRIDE (8 * HWD)              // 8-channel chunk stride
#define NSLOT 256                       // BN partial slots per channel-stat

typedef __attribute__((ext_vector_type(8))) short bf16x8;
typedef __attribute__((ext_vector_type(4))) float f32x4;

__device__ inline unsigned pack2bf(float a, float b) {
  __hip_bfloat162 h2 = __float22bfloat162_rn(float2{a, b});
  unsigned u;
  __builtin_memcpy(&u, &h2, 4);
  return u;
}
__device__ inline unsigned short bf16bits(float a) {
  __hip_bfloat16 h = __float2bfloat16(a);
  unsigned short u;
  __builtin_memcpy(&u, &h, 2);
  return u;
}

// XCD-slab tile mapping: blk%8 = XCD (HW round-robin); each XCD owns 200
// spatially-contiguous tiles (an 80-pixel-row band) so halo re-reads and
// the offconv->dconv offs handoff stay inside one 4MB L2.
__device__ inline void tile_map(int blk, int& b, int& ty0, int& tx0) {
  int t = (blk & 7) * 200 + (blk >> 3);
  b = t / 400;
  int r = t % 400;
  ty0 = (r / 10) * 4;
  tx0 = (r % 10) * 16;
}

// ---------------------------------------------------------------------------
// prep: prepacked MFMA B-fragments (K permuted to kappa = tap*8 + ch within
// each 8-ch chunk, 96-padded; taps 9..11 zero) + zero the BN partial slots.
// ---------------------------------------------------------------------------
__global__ void prep_kernel(const float* __restrict__ cw,
                            const float* __restrict__ ow,
                            unsigned short* __restrict__ Bp,
                            unsigned short* __restrict__ B2p,
                            float* __restrict__ part) {
  int i = blockIdx.x * 256 + threadIdx.x;
  if (i < 32768) part[i] = 0.f;
  if (i < 49152) {                      // dconv weights conv_w[n][c][t], nt 0..3
    int j = i & 7, l = (i >> 3) & 63, rest = i >> 9;
    int ki = rest % 24, nt = rest / 24;
    int kp = ki * 32 + ((l >> 4) << 3) + j;
    int chunk = kp / 96, kq = kp % 96;
    int t = kq >> 3, c = kq & 7;
    int n = nt * 16 + (l & 15);
    float v = (t < 9) ? cw[n * 576 + (chunk * 8 + c) * 9 + t] : 0.f;
    Bp[i] = bf16bits(v);
  }
  if (i < 24576) {                      // offconv weights, nt 0..1, n<18
    int j = i & 7, l = (i >> 3) & 63, rest = i >> 9;
    int ki = rest % 24, nt = rest / 24;
    int kp = ki * 32 + ((l >> 4) << 3) + j;
    int chunk = kp / 96, kq = kp % 96;
    int t = kq >> 3, c = kq & 7;
    int n = nt * 16 + (l & 15);
    float v = (t < 9 && n < 18) ? ow[n * 576 + (chunk * 8 + c) * 9 + t] : 0.f;
    B2p[i] = bf16bits(v);
  }
}

// ---------------------------------------------------------------------------
// offconv implicit GEMM, M=64 (16x4), N=32 (18 used), K=576 pad 768.
// Channel-interleaved patch: pixel stride 12 floats -> tap read = 2x float4.
// ---------------------------------------------------------------------------
__global__ __launch_bounds__(256) void offconv_kernel(
    const float* __restrict__ d, const bf16x8* __restrict__ B2p,
    float* __restrict__ off_out) {
  int b, ty0, tx0;
  tile_map(blockIdx.x, b, ty0, tx0);
  const int tid = threadIdx.x;
  const int wv = tid >> 6, lane = tid & 63;
  const int lo = lane >> 4, li = lane & 15;
  const int px = li, py = wv;

  __shared__ float p2[108 * 12];       // 6r x 18c pixels x 12 (8ch + pad)
  __shared__ bf16x8 Af[768];

  int poff[3];
  bool tre[3];
#pragma unroll
  for (int kk = 0; kk < 3; ++kk) {
    int t = kk * 4 + lo;
    tre[kk] = (t < 9);
    poff[kk] = tre[kk] ? ((py + t / 3) * 18 + px + t % 3) : 0;
  }

  int goff[4], laddr[4];
  bool gok[4];
#pragma unroll
  for (int i = 0; i < 4; ++i) {
    int l = tid + i * 256;
    int c = l / 108, rc = l % 108, r = rc / 18, col = rc % 18;
    int gy = ty0 - 1 + r, gx = tx0 - 1 + col;
    gok[i] = (l < 864) && gy >= 0 && gy < HH && gx >= 0 && gx < WW;
    goff[i] = ((b * 64 + c) * HH + gy) * WW + gx;
    laddr[i] = rc * 12 + c;
  }
  float g[4];
#pragma unroll
  for (int i = 0; i < 4; ++i) g[i] = gok[i] ? d[goff[i]] : 0.f;

  f32x4 acc0{0.f, 0.f, 0.f, 0.f}, acc1{0.f, 0.f, 0.f, 0.f};
  const int nt = wv >> 1, mh = wv & 1;

  for (int chunk = 0; chunk < 8; ++chunk) {
    bf16x8 bw0 = B2p[((nt * 24 + chunk * 3 + 0) << 6) + lane];
    bf16x8 bw1 = B2p[((nt * 24 + chunk * 3 + 1) << 6) + lane];
    bf16x8 bw2 = B2p[((nt * 24 + chunk * 3 + 2) << 6) + lane];
#pragma unroll
    for (int i = 0; i < 4; ++i) {
      int l = tid + i * 256;
      if (l < 864) p2[laddr[i]] = g[i];
    }
    __syncthreads();
    int nco = ((chunk < 7) ? (chunk + 1) : 7) * CHSTRIDE;
#pragma unroll
    for (int i = 0; i < 4; ++i) g[i] = gok[i] ? d[goff[i] + nco] : 0.f;
#pragma unroll
    for (int kk = 0; kk < 3; ++kk) {
      union { bf16x8 v; unsigned u[4]; } a;
      if (tre[kk]) {
        const float* q = p2 + poff[kk] * 12;
        float4 c0 = *(const float4*)(q);
        float4 c1 = *(const float4*)(q + 4);
        a.u[0] = pack2bf(c0.x, c0.y);
        a.u[1] = pack2bf(c0.z, c0.w);
        a.u[2] = pack2bf(c1.x, c1.y);
        a.u[3] = pack2bf(c1.z, c1.w);
      } else {
        a.u[0] = a.u[1] = a.u[2] = a.u[3] = 0u;
      }
      Af[((wv * 3 + kk) << 6) + lane] = a.v;
    }
    __syncthreads();
#pragma unroll
    for (int kk = 0; kk < 3; ++kk) {
      bf16x8 bw = (kk == 0) ? bw0 : (kk == 1) ? bw1 : bw2;
      acc0 = __builtin_amdgcn_mfma_f32_16x16x32_bf16(
          Af[(((mh * 2) * 3 + kk) << 6) + lane], bw, acc0, 0, 0, 0);
      acc1 = __builtin_amdgcn_mfma_f32_16x16x32_bf16(
          Af[(((mh * 2 + 1) * 3 + kk) << 6) + lane], bw, acc1, 0, 0, 0);
    }
  }
  const int n = nt * 16 + li;
  if (n < 18) {
#pragma unroll
    for (int f = 0; f < 2; ++f) {
      int mf = mh * 2 + f;
      f32x4 a = f ? acc1 : acc0;
      float* po = off_out + ((b * 18 + n) * HH + ty0 + mf) * WW + tx0 + lo * 4;
      float4 v;
      v.x = fminf(1.f, fmaxf(-1.f, a[0]));
      v.y = fminf(1.f, fmaxf(-1.f, a[1]));
      v.z = fminf(1.f, fmaxf(-1.f, a[2]));
      v.w = fminf(1.f, fmaxf(-1.f, a[3]));
      *(float4*)po = v;
    }
  }
}

// ---------------------------------------------------------------------------
// dconv implicit GEMM, M=64 (16x4), N=64, K=576 pad 768, grid 1600 (1D,
// XCD-slab swizzled). Channel-interleaved patch: each bilinear corner is
// 2x float4 LDS reads, bank-conflict-free. BN partial sums fused into
// epilogue (xor-shuffle reduce + f32 atomics into 256-slot partial array).
// ---------------------------------------------------------------------------
__global__ __launch_bounds__(256) void dconv_kernel(
    const float* __restrict__ x, const float* __restrict__ offs,
    const bf16x8* __restrict__ Bp, float* __restrict__ out,
    float* __restrict__ part) {
  int b, ty0, tx0;
  tile_map(blockIdx.x, b, ty0, tx0);
  const int tid = threadIdx.x;
  const int wv = tid >> 6, lane = tid & 63;
  const int lo = lane >> 4, li = lane & 15;
  const int px = li, py = wv;
  const int h = ty0 + py, w = tx0 + px;

  __shared__ float patch[189 * 12];    // 9r x 21c pixels x 12 (8ch + pad)
  __shared__ bf16x8 Af[768];

  int bs[3];
  float W00[3], W01[3], W10[3], W11[3];
  bool tre[3];
#pragma unroll
  for (int kk = 0; kk < 3; ++kk) {
    int t = kk * 4 + lo;
    tre[kk] = (t < 9);
    if (tre[kk]) {
      float dy = offs[((b * 18 + 2 * t) * HH + h) * WW + w];
      float dx = offs[((b * 18 + 2 * t + 1) * HH + h) * WW + w];
      float pyf = (float)(h - 1 + t / 3) + dy;
      float pxf = (float)(w - 1 + t % 3) + dx;
      float y0 = floorf(pyf), x0 = floorf(pxf);
      float wy = pyf - y0, wx = pxf - x0;
      bs[kk] = ((int)y0 - (ty0 - 2)) * 21 + ((int)x0 - (tx0 - 2));
      W00[kk] = (1.f - wy) * (1.f - wx);
      W01[kk] = (1.f - wy) * wx;
      W10[kk] = wy * (1.f - wx);
      W11[kk] = wy * wx;
    } else {
      bs[kk] = 0;
      W00[kk] = W01[kk] = W10[kk] = W11[kk] = 0.f;
    }
  }

  int goff[6], laddr[6];
  bool gok[6];
#pragma unroll
  for (int i = 0; i < 6; ++i) {
    int l = tid + i * 256;
    int c = l / 189, rc = l % 189, r = rc / 21, col = rc % 21;
    int gy = ty0 - 2 + r, gx = tx0 - 2 + col;
    gok[i] = (l < 1512) && gy >= 0 && gy < HH && gx >= 0 && gx < WW;
    goff[i] = ((b * 64 + c) * HH + gy) * WW + gx;
    laddr[i] = rc * 12 + c;
  }
  float g[6];
#pragma unroll
  for (int i = 0; i < 6; ++i) g[i] = gok[i] ? x[goff[i]] : 0.f;

  f32x4 acc[4];
#pragma unroll
  for (int i = 0; i < 4; ++i) acc[i] = f32x4{0.f, 0.f, 0.f, 0.f};
  const int nt = wv;

  for (int chunk = 0; chunk < 8; ++chunk) {
    bf16x8 bw0 = Bp[((nt * 24 + chunk * 3 + 0) << 6) + lane];
    bf16x8 bw1 = Bp[((nt * 24 + chunk * 3 + 1) << 6) + lane];
    bf16x8 bw2 = Bp[((nt * 24 + chunk * 3 + 2) << 6) + lane];
#pragma unroll
    for (int i = 0; i < 6; ++i) {
      int l = tid + i * 256;
      if (l < 1512) patch[laddr[i]] = g[i];
    }
    __syncthreads();
    int nco = ((chunk < 7) ? (chunk + 1) : 7) * CHSTRIDE;
#pragma unroll
    for (int i = 0; i < 6; ++i) g[i] = gok[i] ? x[goff[i] + nco] : 0.f;
#pragma unroll
    for (int kk = 0; kk < 3; ++kk) {
      union { bf16x8 v; unsigned u[4]; } a;
      if (tre[kk]) {
        const float* q = patch + bs[kk] * 12;
        float4 p00a = *(const float4*)(q);         // corner (0,0) ch0-3
        float4 p00b = *(const float4*)(q + 4);     //            ch4-7
        float4 p01a = *(const float4*)(q + 12);    // corner (0,1)
        float4 p01b = *(const float4*)(q + 16);
        float4 p10a = *(const float4*)(q + 252);   // corner (1,0): +21*12
        float4 p10b = *(const float4*)(q + 256);
        float4 p11a = *(const float4*)(q + 264);   // corner (1,1)
        float4 p11b = *(const float4*)(q + 268);
        float w0 = W00[kk], w1 = W01[kk], w2 = W10[kk], w3 = W11[kk];
        float v0 = fmaf(w3, p11a.x, fmaf(w2, p10a.x, fmaf(w1, p01a.x, w0 * p00a.x)));
        float v1 = fmaf(w3, p11a.y, fmaf(w2, p10a.y, fmaf(w1, p01a.y, w0 * p00a.y)));
        float v2 = fmaf(w3, p11a.z, fmaf(w2, p10a.z, fmaf(w1, p01a.z, w0 * p00a.z)));
        float v3 = fmaf(w3, p11a.w, fmaf(w2, p10a.w, fmaf(w1, p01a.w, w0 * p00a.w)));
        float v4 = fmaf(w3, p11b.x, fmaf(w2, p10b.x, fmaf(w1, p01b.x, w0 * p00b.x)));
        float v5 = fmaf(w3, p11b.y, fmaf(w2, p10b.y, fmaf(w1, p01b.y, w0 * p00b.y)));
        float v6 = fmaf(w3, p11b.z, fmaf(w2, p10b.z, fmaf(w1, p01b.z, w0 * p00b.z)));
        float v7 = fmaf(w3, p11b.w, fmaf(w2, p10b.w, fmaf(w1, p01b.w, w0 * p00b.w)));
        a.u[0] = pack2bf(v0, v1);
        a.u[1] = pack2bf(v2, v3);
        a.u[2] = pack2bf(v4, v5);
        a.u[3] = pack2bf(v6, v7);
      } else {
        a.u[0] = a.u[1] = a.u[2] = a.u[3] = 0u;
      }
      Af[((wv * 3 + kk) << 6) + lane] = a.v;
    }
    __syncthreads();
#pragma unroll
    for (int kk = 0; kk < 3; ++kk) {
      bf16x8 bw = (kk == 0) ? bw0 : (kk == 1) ? bw1 : bw2;
#pragma unroll
      for (int mf = 0; mf < 4; ++mf)
        acc[mf] = __builtin_amdgcn_mfma_f32_16x16x32_bf16(
            Af[((mf * 3 + kk) << 6) + lane], bw, acc[mf], 0, 0, 0);
    }
  }
  // epilogue: aligned float4 stores + fused BN partial sums
  const int n = nt * 16 + li;
  float s = 0.f, s2 = 0.f;
#pragma unroll
  for (int mf = 0; mf < 4; ++mf) {
    float* po = out + ((b * 64 + n) * HH + ty0 + mf) * WW + tx0 + lo * 4;
    *(float4*)po = make_float4(acc[mf][0], acc[mf][1], acc[mf][2], acc[mf][3]);
#pragma unroll
    for (int r = 0; r < 4; ++r) {
      float v = acc[mf][r];
      s += v;
      s2 = fmaf(v, v, s2);
    }
  }
  // reduce across the 4 lanes (lo=0..3) holding channel n
  s += __shfl_xor(s, 16);  s += __shfl_xor(s, 32);
  s2 += __shfl_xor(s2, 16); s2 += __shfl_xor(s2, 32);
  if (lo == 0) {
    int slot = blockIdx.x & (NSLOT - 1);
    atomicAdd(&part[n * NSLOT + slot], s);
    atomicAdd(&part[(64 + n) * NSLOT + slot], s2);
  }
}

// ---------------------------------------------------------------------------
// reduce BN partials: block j sums part[j][0..255] (f64) -> sums[j]
// ---------------------------------------------------------------------------
__global__ __launch_bounds__(256) void reduce_kernel(
    const float* __restrict__ part, double* __restrict__ sums) {
  const int j = blockIdx.x;
  __shared__ double sh[256];
  sh[threadIdx.x] = (double)part[j * NSLOT + threadIdx.x];
  __syncthreads();
  for (int t = 128; t > 0; t >>= 1) {
    if (threadIdx.x < t) sh[threadIdx.x] += sh[threadIdx.x + t];
    __syncthreads();
  }
  if (threadIdx.x == 0) sums[j] = sh[0];
}

// ---------------------------------------------------------------------------
// BN apply + ReLU, in place on d_out's conv region (float4 vectorized).
// ---------------------------------------------------------------------------
__global__ __launch_bounds__(256) void bnapply_kernel(
    float* __restrict__ out, const double* __restrict__ sums,
    const float* __restrict__ gamma, const float* __restrict__ beta) {
  const int i = blockIdx.x * 256 + threadIdx.x;
  if (i >= OUT_ELEMS / 4) return;
  const int o = (i / (HWD / 4)) & 63;
  const float n_inv = 1.0f / (float)(BB * HWD);
  float mean = (float)sums[o] * n_inv;
  float var = (float)sums[64 + o] * n_inv - mean * mean;
  float inv = gamma[o] * rsqrtf(var + EPSBN);
  float bt = beta[o];
  float4 v = ((float4*)out)[i];
  v.x = fmaxf(0.f, (v.x - mean) * inv + bt);
  v.y = fmaxf(0.f, (v.y - mean) * inv + bt);
  v.z = fmaxf(0.f, (v.z - mean) * inv + bt);
  v.w = fmaxf(0.f, (v.w - mean) * inv + bt);
  ((float4*)out)[i] = v;
}

extern "C" void kernel_launch(void* const* d_in, const int* in_sizes, int n_in,
                              void* d_out, int out_size, void* d_ws, size_t ws_size,
                              hipStream_t stream) {
  const float* x = (const float*)d_in[0];
  const float* d = (const float*)d_in[1];
  const float* ow = (const float*)d_in[2];
  const float* cw = (const float*)d_in[3];
  const float* gamma = (const float*)d_in[4];
  const float* beta = (const float*)d_in[5];

  float* out = (float*)d_out;
  float* off_out = out + OUT_ELEMS;

  // ws: sums double[128] | Bp ush[49152] | B2p ush[24576] | part f32[32768]
  double* sums = (double*)d_ws;
  unsigned short* Bp = (unsigned short*)((char*)d_ws + 1024);
  unsigned short* B2p = Bp + 49152;
  float* part = (float*)(B2p + 24576);

  prep_kernel<<<192, 256, 0, stream>>>(cw, ow, Bp, B2p, part);

  offconv_kernel<<<1600, 256, 0, stream>>>(d, (const bf16x8*)B2p, off_out);
  dconv_kernel<<<1600, 256, 0, stream>>>(x, off_out, (const bf16x8*)Bp, out,
                                         part);

  reduce_kernel<<<128, 256, 0, stream>>>(part, sums);
  bnapply_kernel<<<(OUT_ELEMS / 4 + 255) / 256, 256, 0, stream>>>(
      out, sums, gamma, beta);
}